// Round 5
// baseline (298.678 us; speedup 1.0000x reference)
//
#include <hip/hip_runtime.h>
#include <math.h>

#define BB 4
#define SS 4096
#define DD 128
#define NSPK 9
#define WIN 15
#define EPSN 1e-8f
#define INV_PI 0.31830988618379067f

typedef float vfloat4 __attribute__((ext_vector_type(4)));

// ---------------------------------------------------------------------------
// k_main: one wave handles TWO rows (half-wave of 32 lanes per row).
//   Phase 1 (fill-first): all 64 lanes zero the ENTIRE 16 KB of both rows
//   with unpredicated NT float4 stores — saturates HBM writes from t=0.
//   Phase 2 (branchless band compute): for row i, lane hl in [0,31) handles
//   neighbor j = i-15+hl (clamped loads, arithmetic masking):
//     - dot(x_i,x_j), ||x_j||^2 from raw x; ||x_i||^2 via shfl from hl==15
//     - w = 1 - acos(clamp(dot/(ni*nj)))/pi, masked by window & validity
//     - same-speaker doubling via per-half ballot popcount
//     - deg via half-wave butterfly; store band[row][hl], dinv[row]
//   The band region of out is rewritten with final values by k_bw.
// ---------------------------------------------------------------------------
__global__ __launch_bounds__(256) void k_main(const float* __restrict__ x,
                                              const float* __restrict__ qmask,
                                              const int* __restrict__ dia_len,
                                              float* __restrict__ band,
                                              float* __restrict__ dinv,
                                              float* __restrict__ out) {
    int wid  = (blockIdx.x * blockDim.x + threadIdx.x) >> 6;   // wave id, 0..8191
    int lane = threadIdx.x & 63;

    // ---- phase 1: unconditional zero-fill of both rows (NT streaming) ----
    int rA = wid * 2, rB = rA + 1;
    vfloat4 z = (vfloat4)(0.f);
    vfloat4* oA = (vfloat4*)(out + (size_t)rA * SS);
    vfloat4* oB = (vfloat4*)(out + (size_t)rB * SS);
    #pragma unroll
    for (int it = 0; it < SS / 4 / 64; ++it) {       // 16 iterations
        __builtin_nontemporal_store(z, oA + it * 64 + lane);
        __builtin_nontemporal_store(z, oB + it * 64 + lane);
    }

    // ---- phase 2: branchless band compute ----
    int half = lane >> 5;          // 0: row A, 1: row B
    int hl   = lane & 31;          // position within half
    int row  = rA + half;
    int b    = row >> 12;
    int i    = row & (SS - 1);
    int len  = dia_len[b];

    int  j     = i - WIN + hl;                       // hl==31 -> out of band
    bool inr   = (hl < 31) && (j >= 0) && (j < SS);
    bool maskv = inr && (i < len) && (j < len);
    int  jc    = j < 0 ? 0 : (j > SS - 1 ? SS - 1 : j);

    // speaker of column jc (unconditional, small cached table)
    const float* q = qmask + ((size_t)jc * BB + b) * NSPK;
    int sj = 0; float best = q[0];
    #pragma unroll
    for (int k = 1; k < NSPK; ++k) {
        float qv = q[k];
        if (qv > best) { best = qv; sj = k; }        // first-max tie-break
    }
    int si = __shfl(sj, (lane & 32) + WIN);          // lane where j == i
    bool same = inr && (sj == si);

    // dot(x_i, x_jc) and ||x_jc||^2 (unconditional)
    const float4* xi = (const float4*)(x + (size_t)row * DD);
    const float4* xj = (const float4*)(x + ((size_t)b * SS + jc) * DD);
    float d0 = 0.f, d1 = 0.f, n0 = 0.f, n1 = 0.f;
    #pragma unroll
    for (int d = 0; d < DD / 8; ++d) {
        float4 a0 = xi[2 * d],     c0 = xj[2 * d];
        float4 a1 = xi[2 * d + 1], c1 = xj[2 * d + 1];
        d0 += a0.x * c0.x + a0.y * c0.y + a0.z * c0.z + a0.w * c0.w;
        d1 += a1.x * c1.x + a1.y * c1.y + a1.z * c1.z + a1.w * c1.w;
        n0 += c0.x * c0.x + c0.y * c0.y + c0.z * c0.z + c0.w * c0.w;
        n1 += c1.x * c1.x + c1.y * c1.y + c1.z * c1.z + c1.w * c1.w;
    }
    float dot = d0 + d1;
    float nj2 = n0 + n1;
    float ni2 = __shfl(nj2, (lane & 32) + WIN);      // ||x_i||^2 from j==i lane

    float ni = fmaxf(sqrtf(ni2), EPSN);
    float nj = fmaxf(sqrtf(nj2), EPSN);
    float c  = dot / (ni * nj);
    c = fminf(fmaxf(c, -1.f), 1.f);
    float aij = maskv ? (1.f - acosf(c) * INV_PI) : 0.f;

    // same-speaker count inside window (per half), doubling
    unsigned long long bal = __ballot(maskv && same);
    unsigned long long hm  = half ? 0xFFFFFFFF00000000ull : 0x00000000FFFFFFFFull;
    int cnt = __popcll(bal & hm);
    if (maskv && same && cnt > 1) aij *= 2.f;

    // degree: butterfly within the 32-lane half
    float deg = aij;
    #pragma unroll
    for (int off = 16; off; off >>= 1) deg += __shfl_xor(deg, off);

    band[(size_t)row * 32 + hl] = aij;               // hl==31 writes 0
    if (hl == 0) {
        float dv = (deg == 0.f) ? 1.f : deg;
        dinv[row] = 1.0f / sqrtf(dv);
    }
}

// ---------------------------------------------------------------------------
// k_bw: one wave per row; rewrites the float4-aligned band span with final
// values scaled by dinv_i * dinv_j (zeros at masked positions). ~2.4 MB.
// ---------------------------------------------------------------------------
__global__ __launch_bounds__(256) void k_bw(const float* __restrict__ band,
                                            const float* __restrict__ dinv,
                                            float* __restrict__ out) {
    int row  = (blockIdx.x * blockDim.x + threadIdx.x) >> 6;
    int lane = threadIdx.x & 63;
    if (row >= BB * SS) return;
    int b = row >> 12, i = row & (SS - 1);
    int j0 = i - WIN; if (j0 < 0) j0 = 0;
    int j1 = i + WIN; if (j1 > SS - 1) j1 = SS - 1;
    int fs = j0 >> 2, fe = j1 >> 2;

    int j = fs * 4 + lane;                           // covers [fs*4, fe*4+3]
    if (j > fe * 4 + 3) return;

    float v = 0.f;
    if (j >= j0 && j <= j1) {
        v = band[(size_t)row * 32 + (j - i + WIN)] * dinv[row] * dinv[b * SS + j];
    }
    __builtin_nontemporal_store(v, out + (size_t)row * SS + j);
}

extern "C" void kernel_launch(void* const* d_in, const int* in_sizes, int n_in,
                              void* d_out, int out_size, void* d_ws, size_t ws_size,
                              hipStream_t stream) {
    const float* x       = (const float*)d_in[0];
    const float* qmask   = (const float*)d_in[1];
    const int*   dia_len = (const int*)d_in[2];
    float* out = (float*)d_out;

    char* ws = (char*)d_ws;
    const size_t rows = (size_t)BB * SS;
    float* band = (float*)ws;                        // rows*32 floats (2.1 MB)
    float* dinv = (float*)(ws + rows * 32 * 4);      // rows floats

    k_main<<<(int)(rows / 2 * 64 / 256), 256, 0, stream>>>(x, qmask, dia_len,
                                                           band, dinv, out);
    k_bw  <<<(int)(rows * 64 / 256),     256, 0, stream>>>(band, dinv, out);
}